// Round 6
// baseline (562.538 us; speedup 1.0000x reference)
//
#include <hip/hip_runtime.h>
#include <hip/hip_bf16.h>
#include <cstdint>
#include <cstddef>

// Problem constants
#define CNU 500000      // item id offset
#define CB  65536       // batch
#define CE  128         // embedding dim
#define CF  172         // feature dim
#define EV  64          // events per tile (4 M-tiles of 16)
#define TILES 4         // tiles per block (pipelined)
#define BLKEV (EV*TILES)

typedef unsigned short ushort_t;
typedef __attribute__((ext_vector_type(8))) short b8;    // 8 x bf16
typedef __attribute__((ext_vector_type(4))) short b4;    // 4 x bf16
typedef __attribute__((ext_vector_type(4))) float f4;    // MFMA accumulator

#define MFMA16(a,b,c) __builtin_amdgcn_mfma_f32_16x16x32_bf16((a),(b),(c),0,0,0)

// ---- packed weight layout in ws (ushort elements), B-fragment order:
// frag(nt,kt): lane l holds B[k=kt*32+(l>>4)*8+j][n=nt*16+(l&15)], j=0..7
#define FRAG 512
#define U_KT 18                   // 14 k-tiles wih (K pad 448) + 4 whh
#define U_NT 24
#define U_SZ (U_NT*U_KT*FRAG)
#define PU_OFF 0
#define PI_OFF U_SZ
#define PG_OFF (2*U_SZ)
#define G_SZ (8*8*FRAG)
#define PP_OFF (PG_OFF + G_SZ)
#define P_SZ (8*4*FRAG)

// XOR-swizzle on 16B granules, both write and read sides (T2 discipline).
#define SWZ(r, c) ((c) ^ (((r) & 7) << 3))
#define AFRAG(T, r, c) (*(const b8*)&(T)[(r)][SWZ((r), (c))])

__device__ __forceinline__ unsigned pk2bf(float a, float b) {
  __hip_bfloat162 h = __float22bfloat162_rn(make_float2(a, b));   // v_cvt_pk_bf16_f32
  return *reinterpret_cast<unsigned*>(&h);
}
__device__ __forceinline__ ushort_t f2bf(float f) {
  unsigned u = __float_as_uint(f);
  return (ushort_t)((u + 0x7FFFu + ((u >> 16) & 1u)) >> 16);   // RNE scalar
}
__device__ __forceinline__ float bf2f(ushort_t h) {
  return __uint_as_float(((unsigned)h) << 16);
}
__device__ __forceinline__ float sigmoid_(float x) { return 1.0f/(1.0f+__expf(-x)); }
__device__ __forceinline__ float tanh_(float x) { float e=__expf(2.0f*x); return 1.0f-2.0f/(e+1.0f); }

// ---- LDS: [EV][128] bf16 sub-tiles, 256B rows, XOR-swizzled, single-buffered.
// Reuse: QU hosts h'_u after pred; PU hosts h'_i after gi.
struct __align__(16) SLds {
  ushort_t PU[EV][128];   // proj_user  -> h'_i
  ushort_t PI[EV][128];   // proj_item
  ushort_t FE[EV][192];   // features (cols 172-191 zero, set once)
  ushort_t OU[EV][128];   // old_user (h_u)
  ushort_t OI[EV][128];   // old_item (h_i)
  ushort_t QU[EV][128];   // query_user -> h'_u
};                        // 106,496 B -> 1 block/CU

extern "C" __global__ void prep_weights(
    const float* __restrict__ u_wih, const float* __restrict__ u_whh,
    const float* __restrict__ i_wih, const float* __restrict__ i_whh,
    const float* __restrict__ gate_w, const float* __restrict__ pred_w,
    ushort_t* __restrict__ ws)
{
  const int stride = gridDim.x * blockDim.x;
  const int tid = blockIdx.x * blockDim.x + threadIdx.x;
  for (int i = tid; i < U_SZ; i += stride) {
    const int nt = i / (U_KT*FRAG);
    const int r1 = i - nt*(U_KT*FRAG);
    const int kt = r1 / FRAG;
    const int e  = r1 - kt*FRAG;
    const int l  = e >> 3, j = e & 7;
    const int n  = nt*16 + (l & 15);
    const int k  = (l >> 4)*8 + j;
    float vu, vi;
    if (kt < 14) {
      const int kk = kt*32 + k;
      vu = (kk < 428) ? u_wih[(size_t)n*428 + kk] : 0.0f;
      vi = (kk < 428) ? i_wih[(size_t)n*428 + kk] : 0.0f;
    } else {
      const int kk = (kt - 14)*32 + k;
      vu = u_whh[(size_t)n*128 + kk];
      vi = i_whh[(size_t)n*128 + kk];
    }
    ws[PU_OFF + i] = f2bf(vu);
    ws[PI_OFF + i] = f2bf(vi);
  }
  for (int i = tid; i < G_SZ; i += stride) {
    const int nt = i / (8*FRAG);
    const int r1 = i - nt*(8*FRAG);
    const int kt = r1 / FRAG;
    const int e  = r1 - kt*FRAG;
    const int l  = e >> 3, j = e & 7;
    const int n  = nt*16 + (l & 15);
    const int kk = kt*32 + (l >> 4)*8 + j;
    ws[PG_OFF + i] = f2bf(gate_w[(size_t)n*256 + kk]);
  }
  for (int i = tid; i < P_SZ; i += stride) {
    const int nt = i / (4*FRAG);
    const int r1 = i - nt*(4*FRAG);
    const int kt = r1 / FRAG;
    const int e  = r1 - kt*FRAG;
    const int l  = e >> 3, j = e & 7;
    const int n  = nt*16 + (l & 15);
    const int kk = kt*32 + (l >> 4)*8 + j;
    ws[PP_OFF + i] = f2bf(pred_w[(size_t)n*128 + kk]);
  }
}

// Persistent pipelined block: 4 tiles of 64 events; tile t+1 staged into
// registers during tile t's compute (T14 issue-early/write-late), LDS
// single-buffered. grid=256 (1 block/CU, all resident).
extern "C" __global__ void __launch_bounds__(512, 2)
jodie_main(const int* __restrict__ user_ids, const int* __restrict__ item_ids,
           const float* __restrict__ timestamps, const float* __restrict__ features,
           const int* __restrict__ query_time, const float* __restrict__ memv,
           const float* __restrict__ last_time, const float* __restrict__ time_w,
           const float* __restrict__ u_bih, const float* __restrict__ u_bhh,
           const float* __restrict__ i_bih, const float* __restrict__ i_bhh,
           const float* __restrict__ gate_b, const float* __restrict__ pred_b,
           const ushort_t* __restrict__ ws, float* __restrict__ d_out)
{
  __shared__ SLds s;
  const int t    = threadIdx.x;
  const int base = blockIdx.x * BLKEV;
  const int se   = t >> 4;          // staging event within 32-half
  const int sc8  = (t & 15) * 8;    // staging col base
  const float qt = (float)query_time[0];

  // staging-side time_w (per-thread constant)
  const float4 tws0 = *(const float4*)&time_w[sc8];
  const float4 tws1 = *(const float4*)&time_w[sc8 + 4];
  const float twv[8] = {tws0.x,tws0.y,tws0.z,tws0.w, tws1.x,tws1.y,tws1.z,tws1.w};

  // ---- staging helpers (2 events/thread: ep half 0/1) ----
  auto ids_load = [&](int ev0, int (&nu)[2], int (&ni)[2], float (&nts)[2]) {
#pragma unroll
    for (int ep = 0; ep < 2; ++ep) {
      const int ge = ev0 + ep*32 + se;
      nu[ep]  = user_ids[ge];
      ni[ep]  = item_ids[ge] + CNU;
      nts[ep] = timestamps[ge];
    }
  };
  auto lt_load = [&](const int (&nu)[2], const int (&ni)[2],
                     float (&nlu)[2], float (&nli)[2]) {
#pragma unroll
    for (int ep = 0; ep < 2; ++ep) {
      nlu[ep] = last_time[nu[ep]];
      nli[ep] = last_time[ni[ep]];
    }
  };
  auto mem_load = [&](const int (&nu)[2], const int (&ni)[2], float4 (&mo)[2][4]) {
#pragma unroll
    for (int ep = 0; ep < 2; ++ep) {
      mo[ep][0] = *(const float4*)&memv[(size_t)nu[ep]*CE + sc8];
      mo[ep][1] = *(const float4*)&memv[(size_t)nu[ep]*CE + sc8 + 4];
      mo[ep][2] = *(const float4*)&memv[(size_t)ni[ep]*CE + sc8];
      mo[ep][3] = *(const float4*)&memv[(size_t)ni[ep]*CE + sc8 + 4];
    }
  };
  auto feat_load = [&](int ev0, float4 (&ff)[6]) {
#pragma unroll
    for (int j = 0; j < 6; ++j) {
      const int i = t + 512*j;
      if (i < EV*43) {
        const int e = i / 43, q = i - e*43;
        ff[j] = *(const float4*)&features[(size_t)(ev0 + e)*CF + q*4];
      }
    }
  };
  auto stage_write = [&](const float4 (&mo)[2][4], const float (&nts)[2],
                         const float (&nlu)[2], const float (&nli)[2],
                         const float4 (&ff)[6]) {
#pragma unroll
    for (int ep = 0; ep < 2; ++ep) {
      const int e = ep*32 + se;
      const float du = nts[ep] - nlu[ep];
      const float di = nts[ep] - nli[ep];
      const float dq = qt - nlu[ep];
      const float ouv[8] = {mo[ep][0].x,mo[ep][0].y,mo[ep][0].z,mo[ep][0].w,
                            mo[ep][1].x,mo[ep][1].y,mo[ep][1].z,mo[ep][1].w};
      const float oiv[8] = {mo[ep][2].x,mo[ep][2].y,mo[ep][2].z,mo[ep][2].w,
                            mo[ep][3].x,mo[ep][3].y,mo[ep][3].z,mo[ep][3].w};
      union U8 { unsigned q[4]; b8 v; } xu, xi, hu, hi, qv;
#pragma unroll
      for (int j = 0; j < 8; j += 2) {
        xu.q[j>>1] = pk2bf(ouv[j]*(1.0f + du*twv[j]), ouv[j+1]*(1.0f + du*twv[j+1]));
        xi.q[j>>1] = pk2bf(oiv[j]*(1.0f + di*twv[j]), oiv[j+1]*(1.0f + di*twv[j+1]));
        hu.q[j>>1] = pk2bf(ouv[j], ouv[j+1]);
        hi.q[j>>1] = pk2bf(oiv[j], oiv[j+1]);
        qv.q[j>>1] = pk2bf(ouv[j]*(1.0f + dq*twv[j]), ouv[j+1]*(1.0f + dq*twv[j+1]));
      }
      *(b8*)&s.PU[e][SWZ(e, sc8)] = xu.v;
      *(b8*)&s.PI[e][SWZ(e, sc8)] = xi.v;
      *(b8*)&s.OU[e][SWZ(e, sc8)] = hu.v;
      *(b8*)&s.OI[e][SWZ(e, sc8)] = hi.v;
      *(b8*)&s.QU[e][SWZ(e, sc8)] = qv.v;
    }
#pragma unroll
    for (int j = 0; j < 6; ++j) {
      const int i = t + 512*j;
      if (i < EV*43) {
        const int e = i / 43, q = i - e*43;
        union { unsigned q2[2]; b4 v; } fb;
        fb.q2[0] = pk2bf(ff[j].x, ff[j].y);
        fb.q2[1] = pk2bf(ff[j].z, ff[j].w);
        *(b4*)&s.FE[e][SWZ(e, q*4)] = fb.v;
      }
    }
  };

  // ---- prologue: FE pad zeros (persist across tiles) + stage tile 0 ----
  for (int i = t; i < EV*20; i += 512) {
    const int e = i / 20, c = 172 + (i - e*20);
    s.FE[e][SWZ(e, c)] = 0;
  }
  {
    int nu[2], ni[2]; float nts[2], nlu[2], nli[2]; float4 mo[2][4], ff[6];
    ids_load(base, nu, ni, nts);
    lt_load(nu, ni, nlu, nli);
    mem_load(nu, ni, mo);
    feat_load(base, ff);
    stage_write(mo, nts, nlu, nli, ff);
  }
  __syncthreads();   // B1: tile 0 staged

  // ---- compute-side identity ----
  const int wv   = t >> 6, l = t & 63;
  const int lrow = l & 15;
  const int lk   = (l >> 4) * 8;
  const int col  = wv*16 + lrow;

  const float bru = u_bih[col]     + u_bhh[col];
  const float bzu = u_bih[col+128] + u_bhh[col+128];
  const float bnu = u_bih[col+256];
  const float bhu = u_bhh[col+256];
  const float bri = i_bih[col]     + i_bhh[col];
  const float bzi = i_bih[col+128] + i_bhh[col+128];
  const float bni = i_bih[col+256];
  const float bhi = i_bhh[col+256];
  const float bp  = pred_b[col];
  const float gb  = gate_b[col];

  const ushort_t* Wru = ws + PU_OFF + (size_t)(wv     )*U_KT*FRAG + l*8;
  const ushort_t* Wzu = ws + PU_OFF + (size_t)(wv +  8)*U_KT*FRAG + l*8;
  const ushort_t* Wnu = ws + PU_OFF + (size_t)(wv + 16)*U_KT*FRAG + l*8;
  const ushort_t* Wri = ws + PI_OFF + (size_t)(wv     )*U_KT*FRAG + l*8;
  const ushort_t* Wzi = ws + PI_OFF + (size_t)(wv +  8)*U_KT*FRAG + l*8;
  const ushort_t* Wni = ws + PI_OFF + (size_t)(wv + 16)*U_KT*FRAG + l*8;
  const ushort_t* WP  = ws + PP_OFF + (size_t)wv*4*FRAG + l*8;
  const ushort_t* WG  = ws + PG_OFF + (size_t)wv*8*FRAG + l*8;

  float* __restrict__ outu = d_out + (size_t)CB*CE;
  float* __restrict__ outi = d_out + (size_t)2*CB*CE;

#pragma unroll 1
  for (int tile = 0; tile < TILES; ++tile) {
    const int e0 = base + tile*EV;
    const bool more = (tile + 1 < TILES);

    // staging registers for tile t+1
    int nu[2], ni[2]; float nts[2], nlu[2], nli[2]; float4 mo[2][4], ff[6];
    if (more) ids_load(e0 + EV, nu, ni, nts);   // level-1 gather issued

    // ---- pred: qu @ pred_w^T (reads QU) ----
    {
      f4 ap[4];
#pragma unroll
      for (int m = 0; m < 4; ++m) ap[m] = (f4){bp,bp,bp,bp};
#pragma unroll
      for (int kt = 0; kt < 4; ++kt) {
        b8 fp = *(const b8*)(WP + (size_t)kt*FRAG);
#pragma unroll
        for (int m = 0; m < 4; ++m) {
          b8 a = AFRAG(s.QU, m*16 + lrow, 32*kt + lk);
          ap[m] = MFMA16(a, fp, ap[m]);
        }
      }
#pragma unroll
      for (int m = 0; m < 4; ++m)
#pragma unroll
        for (int r4 = 0; r4 < 4; ++r4) {
          const int row = m*16 + (l >> 4)*4 + r4;
          d_out[(size_t)(e0 + row)*CE + col] = ap[m][r4];
        }
    }
    __syncthreads();   // B2: pred reads of QU done

    if (more) lt_load(nu, ni, nlu, nli);        // level-2 gather issued

    // ---- GRU accumulators ----
    f4 aru[4], azu[4], anu[4], ari[4], azi[4], ani[4];
#pragma unroll
    for (int m = 0; m < 4; ++m) {
      aru[m] = (f4){bru,bru,bru,bru};  azu[m] = (f4){bzu,bzu,bzu,bzu};
      anu[m] = (f4){bnu,bnu,bnu,bnu};  ari[m] = (f4){bri,bri,bri,bri};
      azi[m] = (f4){bzi,bzi,bzi,bzi};  ani[m] = (f4){bni,bni,bni,bni};
    }

    // ---- FUSED gi: each A-fragment feeds user (ktu) and item (kti) ----
#define GI_STEP(TILE, pf, ktu, kti)                                            \
    {                                                                          \
      b8 a_[4];                                                                \
      _Pragma("unroll")                                                        \
      for (int m = 0; m < 4; ++m) a_[m] = AFRAG(TILE, m*16 + lrow, 32*(pf) + lk); \
      b8 fru = *(const b8*)(Wru + (size_t)(ktu)*FRAG);                         \
      b8 fzu = *(const b8*)(Wzu + (size_t)(ktu)*FRAG);                         \
      b8 fnu = *(const b8*)(Wnu + (size_t)(ktu)*FRAG);                         \
      b8 fri = *(const b8*)(Wri + (size_t)(kti)*FRAG);                         \
      b8 fzi = *(const b8*)(Wzi + (size_t)(kti)*FRAG);                         \
      b8 fni = *(const b8*)(Wni + (size_t)(kti)*FRAG);                         \
      _Pragma("unroll")                                                        \
      for (int m = 0; m < 4; ++m) {                                            \
        aru[m] = MFMA16(a_[m], fru, aru[m]);                                   \
        azu[m] = MFMA16(a_[m], fzu, azu[m]);                                   \
        anu[m] = MFMA16(a_[m], fnu, anu[m]);                                   \
        ari[m] = MFMA16(a_[m], fri, ari[m]);                                   \
        azi[m] = MFMA16(a_[m], fzi, azi[m]);                                   \
        ani[m] = MFMA16(a_[m], fni, ani[m]);                                   \
      }                                                                        \
    }
#pragma unroll
    for (int pf = 0; pf < 4; ++pf) GI_STEP(s.PU, pf, pf, pf + 4)
#pragma unroll
    for (int pf = 0; pf < 4; ++pf) GI_STEP(s.PI, pf, pf + 4, pf)
#pragma unroll
    for (int pf = 0; pf < 6; ++pf) GI_STEP(s.FE, pf, pf + 8, pf + 8)
#undef GI_STEP

    if (more) { mem_load(nu, ni, mo); feat_load(e0 + EV, ff); }  // level-3 issued

    // ---- user gh + ew -> h'_u into QU; keep h/h' in regs ----
    float hvu[16], hpvu[16], hvi[16], hpvi[16];
    {
      f4 ah[4];
#pragma unroll
      for (int m = 0; m < 4; ++m) ah[m] = (f4){bhu,bhu,bhu,bhu};
#pragma unroll
      for (int kt = 0; kt < 4; ++kt) {
        b8 fr = *(const b8*)(Wru + (size_t)(14+kt)*FRAG);
        b8 fz = *(const b8*)(Wzu + (size_t)(14+kt)*FRAG);
        b8 fn = *(const b8*)(Wnu + (size_t)(14+kt)*FRAG);
#pragma unroll
        for (int m = 0; m < 4; ++m) {
          b8 h = AFRAG(s.OU, m*16 + lrow, 32*kt + lk);
          aru[m] = MFMA16(h, fr, aru[m]);
          azu[m] = MFMA16(h, fz, azu[m]);
          ah[m]  = MFMA16(h, fn, ah[m]);
        }
      }
#pragma unroll
      for (int m = 0; m < 4; ++m)
#pragma unroll
        for (int r4 = 0; r4 < 4; ++r4) {
          const int row = m*16 + (l >> 4)*4 + r4;
          const float rr = sigmoid_(aru[m][r4]);
          const float zz = sigmoid_(azu[m][r4]);
          const float nn = tanh_(anu[m][r4] + rr*ah[m][r4]);
          const float h  = bf2f(s.OU[row][SWZ(row, col)]);
          const float hp = (1.0f - zz)*nn + zz*h;
          hvu [m*4 + r4] = h;
          hpvu[m*4 + r4] = hp;
          s.QU[row][SWZ(row, col)] = f2bf(hp);   // safe: pred done (B2)
        }
    }
    // ---- item gh (ew deferred past B3) ----
    f4 ahi[4];
    {
#pragma unroll
      for (int m = 0; m < 4; ++m) ahi[m] = (f4){bhi,bhi,bhi,bhi};
#pragma unroll
      for (int kt = 0; kt < 4; ++kt) {
        b8 fr = *(const b8*)(Wri + (size_t)(14+kt)*FRAG);
        b8 fz = *(const b8*)(Wzi + (size_t)(14+kt)*FRAG);
        b8 fn = *(const b8*)(Wni + (size_t)(14+kt)*FRAG);
#pragma unroll
        for (int m = 0; m < 4; ++m) {
          b8 h = AFRAG(s.OI, m*16 + lrow, 32*kt + lk);
          ari[m] = MFMA16(h, fr, ari[m]);
          azi[m] = MFMA16(h, fz, azi[m]);
          ahi[m] = MFMA16(h, fn, ahi[m]);
        }
      }
    }
    __syncthreads();   // B3: all waves past gi (PU reads) + ew_u writes

    // ---- item ew -> h'_i into PU ----
#pragma unroll
    for (int m = 0; m < 4; ++m)
#pragma unroll
      for (int r4 = 0; r4 < 4; ++r4) {
        const int row = m*16 + (l >> 4)*4 + r4;
        const float rr = sigmoid_(ari[m][r4]);
        const float zz = sigmoid_(azi[m][r4]);
        const float nn = tanh_(ani[m][r4] + rr*ahi[m][r4]);
        const float h  = bf2f(s.OI[row][SWZ(row, col)]);
        const float hp = (1.0f - zz)*nn + zz*h;
        hvi [m*4 + r4] = h;
        hpvi[m*4 + r4] = hp;
        s.PU[row][SWZ(row, col)] = f2bf(hp);
      }
    __syncthreads();   // B4: h'_u (QU) and h'_i (PU) visible

    // ---- memory gates: shared gate_w fragments, user+item A streams ----
    f4 agu[4], agi[4];
    {
#pragma unroll
      for (int m = 0; m < 4; ++m) { agu[m] = (f4){gb,gb,gb,gb}; agi[m] = agu[m]; }
#pragma unroll
      for (int kt = 0; kt < 8; ++kt) {
        b8 fg = *(const b8*)(WG + (size_t)kt*FRAG);
#pragma unroll
        for (int m = 0; m < 4; ++m) {
          b8 au = (kt < 4) ? AFRAG(s.OU, m*16 + lrow, 32*kt + lk)
                           : AFRAG(s.QU, m*16 + lrow, 32*(kt-4) + lk);
          b8 ai = (kt < 4) ? AFRAG(s.OI, m*16 + lrow, 32*kt + lk)
                           : AFRAG(s.PU, m*16 + lrow, 32*(kt-4) + lk);
          agu[m] = MFMA16(au, fg, agu[m]);
          agi[m] = MFMA16(ai, fg, agi[m]);
        }
      }
    }
    __syncthreads();   // B5: all gate LDS reads done -> tiles free

    // ---- write-late: stage tile t+1 into LDS (overlaps epilogue stores) ----
    if (more) stage_write(mo, nts, nlu, nli, ff);

    // ---- epilogue from registers (no LDS) ----
#pragma unroll
    for (int m = 0; m < 4; ++m)
#pragma unroll
      for (int r4 = 0; r4 < 4; ++r4) {
        const int row = m*16 + (l >> 4)*4 + r4;
        const float gu = sigmoid_(agu[m][r4]);
        const float gi = sigmoid_(agi[m][r4]);
        outu[(size_t)(e0 + row)*CE + col] = gu*hpvu[m*4 + r4] + (1.0f - gu)*hvu[m*4 + r4];
        outi[(size_t)(e0 + row)*CE + col] = gi*hpvi[m*4 + r4] + (1.0f - gi)*hvi[m*4 + r4];
      }
    __syncthreads();   // B1': tile t+1 staged, safe to read next iteration
  }
}

extern "C" void kernel_launch(void* const* d_in, const int* in_sizes, int n_in,
                              void* d_out, int out_size, void* d_ws, size_t ws_size,
                              hipStream_t stream) {
  const int*   user_ids   = (const int*)d_in[0];
  const int*   item_ids   = (const int*)d_in[1];
  const float* timestamps = (const float*)d_in[2];
  const float* features   = (const float*)d_in[3];
  const int*   query_time = (const int*)d_in[4];
  const float* memv       = (const float*)d_in[5];
  const float* last_time  = (const float*)d_in[6];
  const float* time_w     = (const float*)d_in[7];
  const float* u_wih = (const float*)d_in[8];
  const float* u_whh = (const float*)d_in[9];
  const float* u_bih = (const float*)d_in[10];
  const float* u_bhh = (const float*)d_in[11];
  const float* i_wih = (const float*)d_in[12];
  const float* i_whh = (const float*)d_in[13];
  const float* i_bih = (const float*)d_in[14];
  const float* i_bhh = (const float*)d_in[15];
  const float* gate_w = (const float*)d_in[16];
  const float* gate_b = (const float*)d_in[17];
  const float* pred_w = (const float*)d_in[18];
  const float* pred_b = (const float*)d_in[19];
  ushort_t* ws = (ushort_t*)d_ws;
  float* out = (float*)d_out;

  prep_weights<<<dim3(256), dim3(256), 0, stream>>>(u_wih, u_whh, i_wih, i_whh,
                                                    gate_w, pred_w, ws);
  jodie_main<<<dim3(CB/BLKEV), dim3(512), 0, stream>>>(user_ids, item_ids, timestamps,
                                                       features, query_time, memv,
                                                       last_time, time_w,
                                                       u_bih, u_bhh, i_bih, i_bhh,
                                                       gate_b, pred_b, ws, out);
}

// Round 7
// 142.871 us; speedup vs baseline: 3.9374x; 3.9374x over previous
//
#include <hip/hip_runtime.h>
#include <hip/hip_bf16.h>
#include <cstdint>
#include <cstddef>

// Problem constants
#define CNU 500000      // item id offset
#define CB  65536       // batch
#define CE  128         // embedding dim
#define CF  172         // feature dim
#define EV  64          // events per block (4 M-tiles of 16)

typedef unsigned short ushort_t;
typedef __attribute__((ext_vector_type(8))) short b8;    // 8 x bf16
typedef __attribute__((ext_vector_type(4))) short b4;    // 4 x bf16
typedef __attribute__((ext_vector_type(4))) float f4;    // MFMA accumulator
typedef __attribute__((ext_vector_type(4))) float f32x4; // nt-loadable float4

#define MFMA16(a,b,c) __builtin_amdgcn_mfma_f32_16x16x32_bf16((a),(b),(c),0,0,0)

// Non-temporal (stream / evict-first) loads for read-once gather data.
// R6 PMC: FETCH_SIZE=724MB vs ~117MB useful -> memv/feature stream thrashes
// L2/L3 and evicts the ~1MB packed-weight working set; nt protects weights.
#define NTL4(p)   __builtin_nontemporal_load((const f32x4*)(p))
#define NTLI(p)   __builtin_nontemporal_load(p)
#define NTS(v, p) __builtin_nontemporal_store((v), (p))

// ---- packed weight layout in ws (ushort elements), B-fragment order:
// frag(nt,kt): lane l holds B[k=kt*32+(l>>4)*8+j][n=nt*16+(l&15)], j=0..7
#define FRAG 512
#define U_KT 18                   // 14 k-tiles wih (K pad 448) + 4 whh
#define U_NT 24
#define U_SZ (U_NT*U_KT*FRAG)
#define PU_OFF 0
#define PI_OFF U_SZ
#define PG_OFF (2*U_SZ)
#define G_SZ (8*8*FRAG)
#define PP_OFF (PG_OFF + G_SZ)
#define P_SZ (8*4*FRAG)

// XOR-swizzle on 16B granules, both write and read sides (T2 discipline).
#define SWZ(r, c) ((c) ^ (((r) & 7) << 3))
#define AFRAG(T, r, c) (*(const b8*)&(T)[(r)][SWZ((r), (c))])

__device__ __forceinline__ unsigned pk2bf(float a, float b) {
  __hip_bfloat162 h = __float22bfloat162_rn(make_float2(a, b));   // v_cvt_pk_bf16_f32
  return *reinterpret_cast<unsigned*>(&h);
}
__device__ __forceinline__ ushort_t f2bf(float f) {
  unsigned u = __float_as_uint(f);
  return (ushort_t)((u + 0x7FFFu + ((u >> 16) & 1u)) >> 16);   // RNE scalar
}
__device__ __forceinline__ float bf2f(ushort_t h) {
  return __uint_as_float(((unsigned)h) << 16);
}
__device__ __forceinline__ float sigmoid_(float x) { return 1.0f/(1.0f+__expf(-x)); }
__device__ __forceinline__ float tanh_(float x) { float e=__expf(2.0f*x); return 1.0f-2.0f/(e+1.0f); }

// ---- LDS: [EV][128] bf16 sub-tiles, 256B rows, XOR-swizzled.
// Tile reuse: QU hosts h'_u after pred; PU hosts h'_i after gi.
struct __align__(16) SLds {
  ushort_t PU[EV][128];   // proj_user  -> h'_i (after gi)
  ushort_t PI[EV][128];   // proj_item
  ushort_t FE[EV][192];   // features (cols 172-191 zero)
  ushort_t OU[EV][128];   // old_user (h_u)
  ushort_t OI[EV][128];   // old_item (h_i)
  ushort_t QU[EV][128];   // query_user -> h'_u (after pred)
};                        // 106,496 B -> 1 block/CU

extern "C" __global__ void prep_weights(
    const float* __restrict__ u_wih, const float* __restrict__ u_whh,
    const float* __restrict__ i_wih, const float* __restrict__ i_whh,
    const float* __restrict__ gate_w, const float* __restrict__ pred_w,
    ushort_t* __restrict__ ws)
{
  const int stride = gridDim.x * blockDim.x;
  const int tid = blockIdx.x * blockDim.x + threadIdx.x;
  for (int i = tid; i < U_SZ; i += stride) {
    const int nt = i / (U_KT*FRAG);
    const int r1 = i - nt*(U_KT*FRAG);
    const int kt = r1 / FRAG;
    const int e  = r1 - kt*FRAG;
    const int l  = e >> 3, j = e & 7;
    const int n  = nt*16 + (l & 15);
    const int k  = (l >> 4)*8 + j;
    float vu, vi;
    if (kt < 14) {
      const int kk = kt*32 + k;
      vu = (kk < 428) ? u_wih[(size_t)n*428 + kk] : 0.0f;
      vi = (kk < 428) ? i_wih[(size_t)n*428 + kk] : 0.0f;
    } else {
      const int kk = (kt - 14)*32 + k;
      vu = u_whh[(size_t)n*128 + kk];
      vi = i_whh[(size_t)n*128 + kk];
    }
    ws[PU_OFF + i] = f2bf(vu);
    ws[PI_OFF + i] = f2bf(vi);
  }
  for (int i = tid; i < G_SZ; i += stride) {
    const int nt = i / (8*FRAG);
    const int r1 = i - nt*(8*FRAG);
    const int kt = r1 / FRAG;
    const int e  = r1 - kt*FRAG;
    const int l  = e >> 3, j = e & 7;
    const int n  = nt*16 + (l & 15);
    const int kk = kt*32 + (l >> 4)*8 + j;
    ws[PG_OFF + i] = f2bf(gate_w[(size_t)n*256 + kk]);
  }
  for (int i = tid; i < P_SZ; i += stride) {
    const int nt = i / (4*FRAG);
    const int r1 = i - nt*(4*FRAG);
    const int kt = r1 / FRAG;
    const int e  = r1 - kt*FRAG;
    const int l  = e >> 3, j = e & 7;
    const int n  = nt*16 + (l & 15);
    const int kk = kt*32 + (l >> 4)*8 + j;
    ws[PP_OFF + i] = f2bf(pred_w[(size_t)n*128 + kk]);
  }
}

extern "C" __global__ void __launch_bounds__(512, 2)
jodie_main(const int* __restrict__ user_ids, const int* __restrict__ item_ids,
           const float* __restrict__ timestamps, const float* __restrict__ features,
           const int* __restrict__ query_time, const float* __restrict__ memv,
           const float* __restrict__ last_time, const float* __restrict__ time_w,
           const float* __restrict__ u_bih, const float* __restrict__ u_bhh,
           const float* __restrict__ i_bih, const float* __restrict__ i_bhh,
           const float* __restrict__ gate_b, const float* __restrict__ pred_b,
           const ushort_t* __restrict__ ws, float* __restrict__ d_out)
{
  __shared__ SLds s;
  const int t  = threadIdx.x;
  const int e0 = blockIdx.x * EV;

  // ---- stage: 16 threads/event, 8 cols each, 2 event-passes (nt gathers) ----
  {
    const int c8 = (t & 15) * 8;
    const float qt = (float)query_time[0];
    const float4 tw0 = *(const float4*)&time_w[c8];
    const float4 tw1 = *(const float4*)&time_w[c8 + 4];
    const float twv[8] = {tw0.x,tw0.y,tw0.z,tw0.w, tw1.x,tw1.y,tw1.z,tw1.w};
#pragma unroll
    for (int ep = 0; ep < 2; ++ep) {
      const int e  = ep*32 + (t >> 4);
      const int ge = e0 + e;
      const int u   = NTLI(&user_ids[ge]);
      const int itn = NTLI(&item_ids[ge]) + CNU;
      const float ts = NTLI(&timestamps[ge]);
      const float lu = NTLI(&last_time[u]);
      const float li = NTLI(&last_time[itn]);
      const float du = ts - lu, di = ts - li, dq = qt - lu;

      const f32x4 ou0 = NTL4(&memv[(size_t)u  *CE + c8]);
      const f32x4 ou1 = NTL4(&memv[(size_t)u  *CE + c8 + 4]);
      const f32x4 oi0 = NTL4(&memv[(size_t)itn*CE + c8]);
      const f32x4 oi1 = NTL4(&memv[(size_t)itn*CE + c8 + 4]);
      const float ouv[8] = {ou0[0],ou0[1],ou0[2],ou0[3], ou1[0],ou1[1],ou1[2],ou1[3]};
      const float oiv[8] = {oi0[0],oi0[1],oi0[2],oi0[3], oi1[0],oi1[1],oi1[2],oi1[3]};

      union U8 { unsigned q[4]; b8 v; };
      U8 xu, xi, hu, hi, qv;
#pragma unroll
      for (int j = 0; j < 8; j += 2) {
        xu.q[j>>1] = pk2bf(ouv[j]*(1.0f + du*twv[j]), ouv[j+1]*(1.0f + du*twv[j+1]));
        xi.q[j>>1] = pk2bf(oiv[j]*(1.0f + di*twv[j]), oiv[j+1]*(1.0f + di*twv[j+1]));
        hu.q[j>>1] = pk2bf(ouv[j], ouv[j+1]);
        hi.q[j>>1] = pk2bf(oiv[j], oiv[j+1]);
        qv.q[j>>1] = pk2bf(ouv[j]*(1.0f + dq*twv[j]), ouv[j+1]*(1.0f + dq*twv[j+1]));
      }
      *(b8*)&s.PU[e][SWZ(e, c8)] = xu.v;
      *(b8*)&s.PI[e][SWZ(e, c8)] = xi.v;
      *(b8*)&s.OU[e][SWZ(e, c8)] = hu.v;
      *(b8*)&s.OI[e][SWZ(e, c8)] = hi.v;
      *(b8*)&s.QU[e][SWZ(e, c8)] = qv.v;
    }
  }
  // ---- features: exact float4 tiling (172 = 43*4), nt ----
  for (int i = t; i < EV*43; i += 512) {
    const int e = i / 43, q = i - e*43;
    const f32x4 fv = NTL4(&features[(size_t)(e0 + e)*CF + q*4]);
    union { unsigned q2[2]; b4 v; } fb;
    fb.q2[0] = pk2bf(fv[0], fv[1]);
    fb.q2[1] = pk2bf(fv[2], fv[3]);
    *(b4*)&s.FE[e][SWZ(e, q*4)] = fb.v;
  }
  for (int i = t; i < EV*20; i += 512) {
    const int e = i / 20, c = 172 + (i - e*20);
    s.FE[e][SWZ(e, c)] = 0;
  }
  __syncthreads();

  const int wv   = t >> 6, l = t & 63;
  const int lrow = l & 15;
  const int lk   = (l >> 4) * 8;
  const int col  = wv*16 + lrow;

  // ---- pred FIRST (reads QU; QU becomes h'_u storage afterwards) ----
  {
    const float bp = pred_b[col];
    f4 ap[4];
#pragma unroll
    for (int m = 0; m < 4; ++m) ap[m] = (f4){bp,bp,bp,bp};
    const ushort_t* WP = ws + PP_OFF + (size_t)wv*4*FRAG + l*8;
#pragma unroll
    for (int kt = 0; kt < 4; ++kt) {
      b8 fp = *(const b8*)(WP + (size_t)kt*FRAG);
#pragma unroll
      for (int m = 0; m < 4; ++m) {
        b8 a = AFRAG(s.QU, m*16 + lrow, 32*kt + lk);
        ap[m] = MFMA16(a, fp, ap[m]);
      }
    }
#pragma unroll
    for (int m = 0; m < 4; ++m)
#pragma unroll
      for (int r4 = 0; r4 < 4; ++r4) {
        const int row = m*16 + (l >> 4)*4 + r4;
        NTS(ap[m][r4], &d_out[(size_t)(e0 + row)*CE + col]);
      }
  }
  __syncthreads();   // all pred reads of QU done

  // ---- biases ----
  const float bru = u_bih[col]     + u_bhh[col];
  const float bzu = u_bih[col+128] + u_bhh[col+128];
  const float bnu = u_bih[col+256];
  const float bhu = u_bhh[col+256];
  const float bri = i_bih[col]     + i_bhh[col];
  const float bzi = i_bih[col+128] + i_bhh[col+128];
  const float bni = i_bih[col+256];
  const float bhi = i_bhh[col+256];

  f4 aru[4], azu[4], anu[4], ari[4], azi[4], ani[4];
#pragma unroll
  for (int m = 0; m < 4; ++m) {
    aru[m] = (f4){bru,bru,bru,bru};  azu[m] = (f4){bzu,bzu,bzu,bzu};
    anu[m] = (f4){bnu,bnu,bnu,bnu};  ari[m] = (f4){bri,bri,bri,bri};
    azi[m] = (f4){bzi,bzi,bzi,bzi};  ani[m] = (f4){bni,bni,bni,bni};
  }

  const ushort_t* Wru = ws + PU_OFF + (size_t)(wv     )*U_KT*FRAG + l*8;
  const ushort_t* Wzu = ws + PU_OFF + (size_t)(wv +  8)*U_KT*FRAG + l*8;
  const ushort_t* Wnu = ws + PU_OFF + (size_t)(wv + 16)*U_KT*FRAG + l*8;
  const ushort_t* Wri = ws + PI_OFF + (size_t)(wv     )*U_KT*FRAG + l*8;
  const ushort_t* Wzi = ws + PI_OFF + (size_t)(wv +  8)*U_KT*FRAG + l*8;
  const ushort_t* Wni = ws + PI_OFF + (size_t)(wv + 16)*U_KT*FRAG + l*8;

  // ---- FUSED gi: each A-fragment feeds user (kt=ktu) and item (kt=kti) ----
#define GI_STEP(TILE, pf, ktu, kti)                                          \
  {                                                                          \
    b8 a_[4];                                                                \
    _Pragma("unroll")                                                        \
    for (int m = 0; m < 4; ++m) a_[m] = AFRAG(TILE, m*16 + lrow, 32*(pf) + lk); \
    b8 fru = *(const b8*)(Wru + (size_t)(ktu)*FRAG);                         \
    b8 fzu = *(const b8*)(Wzu + (size_t)(ktu)*FRAG);                         \
    b8 fnu = *(const b8*)(Wnu + (size_t)(ktu)*FRAG);                         \
    b8 fri = *(const b8*)(Wri + (size_t)(kti)*FRAG);                         \
    b8 fzi = *(const b8*)(Wzi + (size_t)(kti)*FRAG);                         \
    b8 fni = *(const b8*)(Wni + (size_t)(kti)*FRAG);                         \
    _Pragma("unroll")                                                        \
    for (int m = 0; m < 4; ++m) {                                            \
      aru[m] = MFMA16(a_[m], fru, aru[m]);                                   \
      azu[m] = MFMA16(a_[m], fzu, azu[m]);                                   \
      anu[m] = MFMA16(a_[m], fnu, anu[m]);                                   \
      ari[m] = MFMA16(a_[m], fri, ari[m]);                                   \
      azi[m] = MFMA16(a_[m], fzi, azi[m]);                                   \
      ani[m] = MFMA16(a_[m], fni, ani[m]);                                   \
    }                                                                        \
  }

#pragma unroll
  for (int pf = 0; pf < 4; ++pf) GI_STEP(s.PU, pf, pf, pf + 4)     // pu: user k0-127, item k128-255
#pragma unroll
  for (int pf = 0; pf < 4; ++pf) GI_STEP(s.PI, pf, pf + 4, pf)     // pi: user k128-255, item k0-127
#pragma unroll
  for (int pf = 0; pf < 6; ++pf) GI_STEP(s.FE, pf, pf + 8, pf + 8) // feat
#undef GI_STEP

  // ---- user gh (K=128) + elementwise -> h'_u into QU space ----
  {
    f4 ah[4];
#pragma unroll
    for (int m = 0; m < 4; ++m) ah[m] = (f4){bhu,bhu,bhu,bhu};
#pragma unroll
    for (int kt = 0; kt < 4; ++kt) {
      b8 fr = *(const b8*)(Wru + (size_t)(14+kt)*FRAG);
      b8 fz = *(const b8*)(Wzu + (size_t)(14+kt)*FRAG);
      b8 fn = *(const b8*)(Wnu + (size_t)(14+kt)*FRAG);
#pragma unroll
      for (int m = 0; m < 4; ++m) {
        b8 h = AFRAG(s.OU, m*16 + lrow, 32*kt + lk);
        aru[m] = MFMA16(h, fr, aru[m]);
        azu[m] = MFMA16(h, fz, azu[m]);
        ah[m]  = MFMA16(h, fn, ah[m]);
      }
    }
#pragma unroll
    for (int m = 0; m < 4; ++m)
#pragma unroll
      for (int r4 = 0; r4 < 4; ++r4) {
        const int row = m*16 + (l >> 4)*4 + r4;
        const float rr = sigmoid_(aru[m][r4]);
        const float zz = sigmoid_(azu[m][r4]);
        const float nn = tanh_(anu[m][r4] + rr*ah[m][r4]);
        const float h  = bf2f(s.OU[row][SWZ(row, col)]);
        s.QU[row][SWZ(row, col)] = f2bf((1.0f - zz)*nn + zz*h);
      }
  }
  __syncthreads();   // all waves past gi (PU reads) and ew_u writes

  // ---- item gh + elementwise -> h'_i into PU space ----
  {
    f4 ah[4];
#pragma unroll
    for (int m = 0; m < 4; ++m) ah[m] = (f4){bhi,bhi,bhi,bhi};
#pragma unroll
    for (int kt = 0; kt < 4; ++kt) {
      b8 fr = *(const b8*)(Wri + (size_t)(14+kt)*FRAG);
      b8 fz = *(const b8*)(Wzi + (size_t)(14+kt)*FRAG);
      b8 fn = *(const b8*)(Wni + (size_t)(14+kt)*FRAG);
#pragma unroll
      for (int m = 0; m < 4; ++m) {
        b8 h = AFRAG(s.OI, m*16 + lrow, 32*kt + lk);
        ari[m] = MFMA16(h, fr, ari[m]);
        azi[m] = MFMA16(h, fz, azi[m]);
        ah[m]  = MFMA16(h, fn, ah[m]);
      }
    }
#pragma unroll
    for (int m = 0; m < 4; ++m)
#pragma unroll
      for (int r4 = 0; r4 < 4; ++r4) {
        const int row = m*16 + (l >> 4)*4 + r4;
        const float rr = sigmoid_(ari[m][r4]);
        const float zz = sigmoid_(azi[m][r4]);
        const float nn = tanh_(ani[m][r4] + rr*ah[m][r4]);
        const float h  = bf2f(s.OI[row][SWZ(row, col)]);
        s.PU[row][SWZ(row, col)] = f2bf((1.0f - zz)*nn + zz*h);
      }
  }
  __syncthreads();   // h'_u (QU) and h'_i (PU) visible to all waves

  // ---- memory gates: shared gate_w fragments, user+item A streams ----
  {
    const float gb = gate_b[col];
    f4 agu[4], agi[4];
#pragma unroll
    for (int m = 0; m < 4; ++m) { agu[m] = (f4){gb,gb,gb,gb}; agi[m] = agu[m]; }
    const ushort_t* WG = ws + PG_OFF + (size_t)wv*8*FRAG + l*8;
#pragma unroll
    for (int kt = 0; kt < 8; ++kt) {
      b8 fg = *(const b8*)(WG + (size_t)kt*FRAG);
#pragma unroll
      for (int m = 0; m < 4; ++m) {
        b8 au = (kt < 4) ? AFRAG(s.OU, m*16 + lrow, 32*kt + lk)
                         : AFRAG(s.QU, m*16 + lrow, 32*(kt-4) + lk);
        b8 ai = (kt < 4) ? AFRAG(s.OI, m*16 + lrow, 32*kt + lk)
                         : AFRAG(s.PU, m*16 + lrow, 32*(kt-4) + lk);
        agu[m] = MFMA16(au, fg, agu[m]);
        agi[m] = MFMA16(ai, fg, agi[m]);
      }
    }
    float* __restrict__ outu = d_out + (size_t)CB*CE;
    float* __restrict__ outi = d_out + (size_t)2*CB*CE;
#pragma unroll
    for (int m = 0; m < 4; ++m)
#pragma unroll
      for (int r4 = 0; r4 < 4; ++r4) {
        const int row = m*16 + (l >> 4)*4 + r4;
        const float gu = sigmoid_(agu[m][r4]);
        const float gi = sigmoid_(agi[m][r4]);
        const float hu  = bf2f(s.OU[row][SWZ(row, col)]);
        const float hpu = bf2f(s.QU[row][SWZ(row, col)]);
        const float hi  = bf2f(s.OI[row][SWZ(row, col)]);
        const float hpi = bf2f(s.PU[row][SWZ(row, col)]);
        NTS(gu*hpu + (1.0f - gu)*hu, &outu[(size_t)(e0 + row)*CE + col]);
        NTS(gi*hpi + (1.0f - gi)*hi, &outi[(size_t)(e0 + row)*CE + col]);
      }
  }
}

extern "C" void kernel_launch(void* const* d_in, const int* in_sizes, int n_in,
                              void* d_out, int out_size, void* d_ws, size_t ws_size,
                              hipStream_t stream) {
  const int*   user_ids   = (const int*)d_in[0];
  const int*   item_ids   = (const int*)d_in[1];
  const float* timestamps = (const float*)d_in[2];
  const float* features   = (const float*)d_in[3];
  const int*   query_time = (const int*)d_in[4];
  const float* memv       = (const float*)d_in[5];
  const float* last_time  = (const float*)d_in[6];
  const float* time_w     = (const float*)d_in[7];
  const float* u_wih = (const float*)d_in[8];
  const float* u_whh = (const float*)d_in[9];
  const float* u_bih = (const float*)d_in[10];
  const float* u_bhh = (const float*)d_in[11];
  const float* i_wih = (const float*)d_in[12];
  const float* i_whh = (const float*)d_in[13];
  const float* i_bih = (const float*)d_in[14];
  const float* i_bhh = (const float*)d_in[15];
  const float* gate_w = (const float*)d_in[16];
  const float* gate_b = (const float*)d_in[17];
  const float* pred_w = (const float*)d_in[18];
  const float* pred_b = (const float*)d_in[19];
  ushort_t* ws = (ushort_t*)d_ws;
  float* out = (float*)d_out;

  prep_weights<<<dim3(256), dim3(256), 0, stream>>>(u_wih, u_whh, i_wih, i_whh,
                                                    gate_w, pred_w, ws);
  jodie_main<<<dim3(CB/EV), dim3(512), 0, stream>>>(user_ids, item_ids, timestamps,
                                                    features, query_time, memv,
                                                    last_time, time_w,
                                                    u_bih, u_bhh, i_bih, i_bhh,
                                                    gate_b, pred_b, ws, out);
}